// Round 15
// baseline (116.650 us; speedup 1.0000x reference)
//
#include <hip/hip_runtime.h>

constexpr int NB     = 8 * 32 * 96 * 96;   // 2359296 output elements
constexpr int NQUAD  = NB / 4;             // 589824 quads of 4 adjacent-ho outputs
constexpr int NACC   = 44;                 // 8 sums + 36 upper-tri Gram entries
constexpr int GRID_A = 768;                // 768*256*3 == NQUAD exactly (balanced)
constexpr int TPB    = 256;
constexpr int GRID_P = 768;
constexpr int STRIDE = GRID_A * TPB;       // 196608; NQUAD == 3*STRIDE exactly

// ---- Kernel A: quad reduce; last 44 arrivals each mid-reduce one acc row ----
__global__ __launch_bounds__(TPB, 4)
void reduce_kernel(const float* __restrict__ x, float* __restrict__ partials,
                   double* __restrict__ sums_d, unsigned int* __restrict__ ctr) {
  float acc[NACC];
#pragma unroll
  for (int i = 0; i < NACC; ++i) acc[i] = 0.0f;

  int t = threadIdx.x;
  int tid = blockIdx.x * TPB + t;
#pragma unroll
  for (int it = 0; it < 3; ++it) {          // compile-time trip count -> deep MLP
    int q = tid + it * STRIDE;
    int hq = q % 24;
    int t1 = q / 24;
    int wo = t1 % 96;
    int t2 = t1 / 96;
    int so = t2 % 32;
    int b  = t2 / 32;
    const float* base = x + (((b * 64 + 2 * so) * 192 + 2 * wo) * 192 + 8 * hq);
    float4 a0 = *(const float4*)(base);
    float4 b0 = *(const float4*)(base + 4);
    float4 a1 = *(const float4*)(base + 192);
    float4 b1 = *(const float4*)(base + 196);
    float4 a2 = *(const float4*)(base + 192 * 192);
    float4 b2 = *(const float4*)(base + 192 * 192 + 4);
    float4 a3 = *(const float4*)(base + 192 * 192 + 192);
    float4 b3 = *(const float4*)(base + 192 * 192 + 196);
    float P[4][8] = {
      {a0.x, a0.y, a1.x, a1.y, a2.x, a2.y, a3.x, a3.y},
      {a0.z, a0.w, a1.z, a1.w, a2.z, a2.w, a3.z, a3.w},
      {b0.x, b0.y, b1.x, b1.y, b2.x, b2.y, b3.x, b3.y},
      {b0.z, b0.w, b1.z, b1.w, b2.z, b2.w, b3.z, b3.w}};
#pragma unroll
    for (int a = 0; a < 8; ++a)
      acc[a] += (P[0][a] + P[1][a]) + (P[2][a] + P[3][a]);
    int k = 8;
#pragma unroll
    for (int a = 0; a < 8; ++a)
#pragma unroll
      for (int c = a; c < 8; ++c) {
        float tt = P[0][a] * P[0][c];
        tt += P[1][a] * P[1][c];
        tt += P[2][a] * P[2][c];
        tt += P[3][a] * P[3][c];
        acc[k++] += tt;
      }
  }

  // wave shuffle reduce (64 lanes)
#pragma unroll
  for (int i = 0; i < NACC; ++i) {
    float v = acc[i];
    for (int off = 32; off >= 1; off >>= 1) v += __shfl_down(v, off, 64);
    acc[i] = v;
  }
  __shared__ float lds[4][NACC];
  int lane = t & 63;
  int wv   = t >> 6;
  if (lane == 0) {
#pragma unroll
    for (int i = 0; i < NACC; ++i) lds[wv][i] = acc[i];
  }
  __syncthreads();
  if (t < NACC) {
    float s = lds[0][t] + lds[1][t] + lds[2][t] + lds[3][t];
    partials[t * GRID_A + blockIdx.x] = s;  // transposed: contiguous per-acc rows
  }

  // ---- epilogue: last NACC arrivals each mid-reduce one acc row (parallel CUs) ----
  __threadfence();                          // writers' release (all threads fence)
  __syncthreads();
  __shared__ unsigned int oldv;
  if (t == 0) oldv = atomicAdd(ctr, 1u);
  __syncthreads();
  unsigned int old = oldv;
  if (old < (unsigned int)(GRID_A - NACC)) return;   // 724 blocks retire immediately
  int row = (int)old - (GRID_A - NACC);              // 0..43, unique per block

  if (t == 0) {                              // brief relaxed spin (r11-proven benign)
    while (__hip_atomic_load(ctr, __ATOMIC_RELAXED, __HIP_MEMORY_SCOPE_AGENT)
           < (unsigned int)GRID_A)
      __builtin_amdgcn_s_sleep(1);
  }
  __syncthreads();
  __threadfence();                           // acquire all partials

  double s = 0.0;
  if (t < GRID_A / 4) {                      // 192 threads x 1 float4 = 768 floats
    float4 u = ((const float4*)(partials + row * GRID_A))[t];
    s = (double)u.x + (double)u.y + (double)u.z + (double)u.w;
  }
  for (int off = 32; off >= 1; off >>= 1) s += __shfl_down(s, off, 64);
  __shared__ double ldsd[4];
  if (lane == 0) ldsd[wv] = s;
  __syncthreads();
  if (t == 0) sums_d[row] = ldsd[0] + ldsd[1] + ldsd[2] + ldsd[3];
}

// ---- readlane helper: compile-time lane gather (no LDS round-trip) ----
__device__ __forceinline__ float rdlane(float x, int lane) {
  return __int_as_float(__builtin_amdgcn_readlane(__float_as_int(x), lane));
}

// ---- Jacobi rotation angles: fast-math (v_rcp/v_sqrt/v_rsq), ~12 VALU ----
template <int P, int Q>
__device__ __forceinline__ void jrot(const float (&r)[8], float& ct, float& st) {
  float app = rdlane(r[P], P);
  float aqq = rdlane(r[Q], Q);
  float apq = rdlane(r[Q], P);
  float theta = (aqq - app) * 0.5f * __builtin_amdgcn_rcpf(apq);
  float root  = __builtin_amdgcn_sqrtf(theta * theta + 1.0f);
  float tmag  = __builtin_amdgcn_rcpf(fabsf(theta) + root);
  float tt    = copysignf(tmag, theta);
  float c     = __builtin_amdgcn_rsqf(tt * tt + 1.0f);
  float s     = tt * c;
  bool zero   = (apq == 0.0f);
  ct = zero ? 1.0f : c;
  st = zero ? 0.0f : s;
}

template <int P, int Q>
__device__ __forceinline__ void jcol(float (&r)[8], float (&v)[8], float c, float s) {
  float rp = r[P], rq = r[Q];
  r[P] = c * rp - s * rq;
  r[Q] = s * rp + c * rq;
  float vp = v[P], vq = v[Q];
  v[P] = c * vp - s * vq;
  v[Q] = s * vp + c * vq;
}

template <int P0,int Q0,int P1,int Q1,int P2,int Q2,int P3,int Q3>
__device__ __forceinline__ void jacobi_round(float (&r)[8], float (&v)[8], int i) {
  float c0,s0,c1,s1,c2,s2,c3,s3;
  jrot<P0,Q0>(r, c0, s0);
  jrot<P1,Q1>(r, c1, s1);
  jrot<P2,Q2>(r, c2, s2);
  jrot<P3,Q3>(r, c3, s3);
  jcol<P0,Q0>(r, v, c0, s0);
  jcol<P1,Q1>(r, v, c1, s1);
  jcol<P2,Q2>(r, v, c2, s2);
  jcol<P3,Q3>(r, v, c3, s3);
  float alpha = 1.0f, beta = 0.0f;
  int plane = i;
  if (i == P0) { alpha = c0; beta = -s0; plane = Q0; }
  if (i == Q0) { alpha = c0; beta =  s0; plane = P0; }
  if (i == P1) { alpha = c1; beta = -s1; plane = Q1; }
  if (i == Q1) { alpha = c1; beta =  s1; plane = P1; }
  if (i == P2) { alpha = c2; beta = -s2; plane = Q2; }
  if (i == Q2) { alpha = c2; beta =  s2; plane = P2; }
  if (i == P3) { alpha = c3; beta = -s3; plane = Q3; }
  if (i == Q3) { alpha = c3; beta =  s3; plane = P3; }
  float prow[8];
#pragma unroll
  for (int j = 0; j < 8; ++j) prow[j] = __shfl(r[j], plane, 64);
#pragma unroll
  for (int j = 0; j < 8; ++j) r[j] = alpha * r[j] + beta * prow[j];
}

// ------- Kernel C: redundant per-block eigensolve (wave 0) + quad projection -------
__global__ __launch_bounds__(TPB, 4)
void project_solve_kernel(const float* __restrict__ x,
                          const double* __restrict__ sums_d,
                          float* __restrict__ out,
                          float* __restrict__ out_tail) {
  __shared__ double sums[NACC];
  __shared__ float s_res[9];
  int t = threadIdx.x;

  if (t < NACC) sums[t] = sums_d[t];
  __syncthreads();

  if (t < 64) {   // wave 0 solves; waves 1-3 wait at the barrier
    const int i = t & 7;
    const double invN = 1.0 / (double)NB;
    double mean[8];
#pragma unroll
    for (int j = 0; j < 8; ++j) mean[j] = sums[j] * invN;
    double mean_i = mean[0];
#pragma unroll
    for (int k = 1; k < 8; ++k) if (i == k) mean_i = mean[k];
    double rowd[8];
#pragma unroll
    for (int j = 0; j < 8; ++j) {
      int p = i < j ? i : j;
      int q = i < j ? j : i;
      int idx = 8 + p * 8 - (p * (p - 1)) / 2 + (q - p);
      rowd[j] = sums[idx] - (double)NB * mean_i * mean[j];
    }
    double tr = 0.0;
#pragma unroll
    for (int k = 0; k < 8; ++k) tr += __shfl(rowd[k], k, 64);
    double shift = tr * 0.125;

    float r[8], v[8];
#pragma unroll
    for (int j = 0; j < 8; ++j) {
      double d = rowd[j] - (j == i ? shift : 0.0);
      r[j] = (float)(d * (1.0 / 1536.0));
      v[j] = (j == i) ? 1.0f : 0.0f;
    }
#pragma unroll 1
    for (int sweep = 0; sweep < 5; ++sweep) {
      jacobi_round<7,0, 1,6, 2,5, 3,4>(r, v, i);
      jacobi_round<7,1, 2,0, 3,6, 4,5>(r, v, i);
      jacobi_round<7,2, 3,1, 4,0, 5,6>(r, v, i);
      jacobi_round<7,3, 4,2, 5,1, 6,0>(r, v, i);
      jacobi_round<7,4, 5,3, 6,2, 0,1>(r, v, i);
      jacobi_round<7,5, 6,4, 0,3, 1,2>(r, v, i);
      jacobi_round<7,6, 0,5, 1,4, 2,3>(r, v, i);
    }
    float diag[8];
#pragma unroll
    for (int k = 0; k < 8; ++k) diag[k] = rdlane(r[k], k);
    int best = 0; float bd = diag[0];
#pragma unroll
    for (int k = 1; k < 8; ++k) if (diag[k] > bd) { bd = diag[k]; best = k; }
    float vi = v[0];
#pragma unroll
    for (int k = 1; k < 8; ++k) if (best == k) vi = v[k];
    float vec[8];
#pragma unroll
    for (int k = 0; k < 8; ++k) vec[k] = rdlane(vi, k);
    float nrm2 = 0.0f;
#pragma unroll
    for (int k = 0; k < 8; ++k) nrm2 += vec[k] * vec[k];
    float inv = 1.0f / sqrtf(nrm2);
#pragma unroll
    for (int k = 0; k < 8; ++k) vec[k] *= inv;
    // sign convention (measured vs LAPACK round 1/2): largest-|component| NEGATIVE
    int m = 0; float am = fabsf(vec[0]);
#pragma unroll
    for (int k = 1; k < 8; ++k) { float aa = fabsf(vec[k]); if (aa > am) { am = aa; m = k; } }
    float vm = vec[0];
#pragma unroll
    for (int k = 1; k < 8; ++k) if (m == k) vm = vec[k];
    if (vm > 0.0f) {
#pragma unroll
      for (int k = 0; k < 8; ++k) vec[k] = -vec[k];
    }
    double c0d = 0.0;
#pragma unroll
    for (int k = 0; k < 8; ++k) c0d += mean[k] * (double)vec[k];
    float mi = (float)mean[0];
#pragma unroll
    for (int k = 1; k < 8; ++k) if (i == k) mi = (float)mean[k];
    float vl = vec[0];
#pragma unroll
    for (int k = 1; k < 8; ++k) if (i == k) vl = vec[k];

    if (t < 8) {
      s_res[t] = vl;
      if (blockIdx.x == 0) {
        out_tail[t]     = mi;   // mean
        out_tail[8 + t] = vl;   // pca_components
      }
    }
    if (t == 0) s_res[8] = (float)c0d;
  }
  __syncthreads();

  // quad projection: compile-time 3 iters, 8x float4 loads -> float4 store
  float w0 = s_res[0], w1 = s_res[1], w2 = s_res[2], w3 = s_res[3];
  float w4 = s_res[4], w5 = s_res[5], w6 = s_res[6], w7 = s_res[7];
  float c0 = s_res[8];
  float4* out4 = (float4*)out;
  int tid = blockIdx.x * TPB + t;
#pragma unroll
  for (int it = 0; it < 3; ++it) {
    int q = tid + it * STRIDE;
    int hq = q % 24;
    int t1 = q / 24;
    int wo = t1 % 96;
    int t2 = t1 / 96;
    int so = t2 % 32;
    int b  = t2 / 32;
    const float* base = x + (((b * 64 + 2 * so) * 192 + 2 * wo) * 192 + 8 * hq);
    float4 a0 = *(const float4*)(base);
    float4 b0 = *(const float4*)(base + 4);
    float4 a1 = *(const float4*)(base + 192);
    float4 b1 = *(const float4*)(base + 196);
    float4 a2 = *(const float4*)(base + 192 * 192);
    float4 b2 = *(const float4*)(base + 192 * 192 + 4);
    float4 a3 = *(const float4*)(base + 192 * 192 + 192);
    float4 b3 = *(const float4*)(base + 192 * 192 + 196);
    float o0 = a0.x * w0 + a0.y * w1 + a1.x * w2 + a1.y * w3
             + a2.x * w4 + a2.y * w5 + a3.x * w6 + a3.y * w7 - c0;
    float o1 = a0.z * w0 + a0.w * w1 + a1.z * w2 + a1.w * w3
             + a2.z * w4 + a2.w * w5 + a3.z * w6 + a3.w * w7 - c0;
    float o2 = b0.x * w0 + b0.y * w1 + b1.x * w2 + b1.y * w3
             + b2.x * w4 + b2.y * w5 + b3.x * w6 + b3.y * w7 - c0;
    float o3 = b0.z * w0 + b0.w * w1 + b1.z * w2 + b1.w * w3
             + b2.z * w4 + b2.w * w5 + b3.z * w6 + b3.w * w7 - c0;
    out4[q] = make_float4(o0, o1, o2, o3);
  }
}

extern "C" void kernel_launch(void* const* d_in, const int* in_sizes, int n_in,
                              void* d_out, int out_size, void* d_ws, size_t ws_size,
                              hipStream_t stream) {
  (void)in_sizes; (void)n_in; (void)out_size; (void)ws_size;
  const float* x = (const float*)d_in[0];
  float* out = (float*)d_out;
  float* partials   = (float*)d_ws;                          // 44*768 f32 = 135 KB
  double* sums_d    = (double*)(partials + NACC * GRID_A);   // 44 f64 (8B-aligned)
  unsigned int* ctr = (unsigned int*)(sums_d + NACC);        // u32

  hipMemsetAsync((void*)ctr, 0, sizeof(unsigned int), stream);  // captured memset node
  reduce_kernel<<<GRID_A, TPB, 0, stream>>>(x, partials, sums_d, ctr);
  project_solve_kernel<<<GRID_P, TPB, 0, stream>>>(x, sums_d, out, out + NB);
}

// Round 16
// 51.074 us; speedup vs baseline: 2.2839x; 2.2839x over previous
//
#include <hip/hip_runtime.h>

constexpr int NB     = 8 * 32 * 96 * 96;   // 2359296 output elements
constexpr int NQUAD  = NB / 4;             // 589824 quads of 4 adjacent-ho outputs
constexpr int NACC   = 44;                 // 8 sums + 36 upper-tri Gram entries
constexpr int GRID_A = 768;                // 768*256*3 == NQUAD exactly (balanced)
constexpr int TPB    = 256;
constexpr int GRID_P = 768;
constexpr int STRIDE = GRID_A * TPB;       // 196608; NQUAD == 3*STRIDE exactly

// ---------------- Kernel A: sums + Gram partial reduction (quad/float4x8) ----------------
__global__ __launch_bounds__(TPB, 4)
void reduce_kernel(const float* __restrict__ x, float* __restrict__ partials) {
  float acc[NACC];
#pragma unroll
  for (int i = 0; i < NACC; ++i) acc[i] = 0.0f;

  int t = threadIdx.x;
  int tid = blockIdx.x * TPB + t;
#pragma unroll
  for (int it = 0; it < 3; ++it) {          // compile-time trip count -> deep MLP
    int q = tid + it * STRIDE;
    int hq = q % 24;
    int t1 = q / 24;
    int wo = t1 % 96;
    int t2 = t1 / 96;
    int so = t2 % 32;
    int b  = t2 / 32;
    const float* base = x + (((b * 64 + 2 * so) * 192 + 2 * wo) * 192 + 8 * hq);
    float4 a0 = *(const float4*)(base);
    float4 b0 = *(const float4*)(base + 4);
    float4 a1 = *(const float4*)(base + 192);
    float4 b1 = *(const float4*)(base + 196);
    float4 a2 = *(const float4*)(base + 192 * 192);
    float4 b2 = *(const float4*)(base + 192 * 192 + 4);
    float4 a3 = *(const float4*)(base + 192 * 192 + 192);
    float4 b3 = *(const float4*)(base + 192 * 192 + 196);
    float P[4][8] = {
      {a0.x, a0.y, a1.x, a1.y, a2.x, a2.y, a3.x, a3.y},
      {a0.z, a0.w, a1.z, a1.w, a2.z, a2.w, a3.z, a3.w},
      {b0.x, b0.y, b1.x, b1.y, b2.x, b2.y, b3.x, b3.y},
      {b0.z, b0.w, b1.z, b1.w, b2.z, b2.w, b3.z, b3.w}};
#pragma unroll
    for (int a = 0; a < 8; ++a)
      acc[a] += (P[0][a] + P[1][a]) + (P[2][a] + P[3][a]);
    int k = 8;
#pragma unroll
    for (int a = 0; a < 8; ++a)
#pragma unroll
      for (int c = a; c < 8; ++c) {
        float tt = P[0][a] * P[0][c];
        tt += P[1][a] * P[1][c];
        tt += P[2][a] * P[2][c];
        tt += P[3][a] * P[3][c];
        acc[k++] += tt;
      }
  }

  // wave shuffle reduce (64 lanes)
#pragma unroll
  for (int i = 0; i < NACC; ++i) {
    float v = acc[i];
    for (int off = 32; off >= 1; off >>= 1) v += __shfl_down(v, off, 64);
    acc[i] = v;
  }
  __shared__ float lds[4][NACC];
  int lane = t & 63;
  int wv   = t >> 6;
  if (lane == 0) {
#pragma unroll
    for (int i = 0; i < NACC; ++i) lds[wv][i] = acc[i];
  }
  __syncthreads();
  if (t < NACC) {
    float s = lds[0][t] + lds[1][t] + lds[2][t] + lds[3][t];
    partials[t * GRID_A + blockIdx.x] = s;  // transposed: contiguous per-acc rows
  }
}

// ------- Kernel A2: per-acc parallel reduce, 44 blocks -> sums_d (f64) -------
__global__ __launch_bounds__(TPB)
void mid_reduce_kernel(const float* __restrict__ partials, double* __restrict__ sums_d) {
  int a = blockIdx.x;
  int t = threadIdx.x;
  const float* row = partials + a * GRID_A;
  double s = (double)row[t] + (double)row[t + 256] + (double)row[t + 512];
  for (int off = 32; off >= 1; off >>= 1) s += __shfl_down(s, off, 64);
  __shared__ double lds[4];
  if ((t & 63) == 0) lds[t >> 6] = s;
  __syncthreads();
  if (t == 0) sums_d[a] = lds[0] + lds[1] + lds[2] + lds[3];
}

// ---- readlane helper: compile-time lane gather (no LDS round-trip) ----
__device__ __forceinline__ float rdlane(float x, int lane) {
  return __int_as_float(__builtin_amdgcn_readlane(__float_as_int(x), lane));
}

// ---- Jacobi rotation angles: fast-math (v_rcp/v_sqrt/v_rsq), ~12 VALU ----
template <int P, int Q>
__device__ __forceinline__ void jrot(const float (&r)[8], float& ct, float& st) {
  float app = rdlane(r[P], P);
  float aqq = rdlane(r[Q], Q);
  float apq = rdlane(r[Q], P);
  float theta = (aqq - app) * 0.5f * __builtin_amdgcn_rcpf(apq);
  float root  = __builtin_amdgcn_sqrtf(theta * theta + 1.0f);
  float tmag  = __builtin_amdgcn_rcpf(fabsf(theta) + root);
  float tt    = copysignf(tmag, theta);
  float c     = __builtin_amdgcn_rsqf(tt * tt + 1.0f);
  float s     = tt * c;
  bool zero   = (apq == 0.0f);
  ct = zero ? 1.0f : c;
  st = zero ? 0.0f : s;
}

template <int P, int Q>
__device__ __forceinline__ void jcol(float (&r)[8], float (&v)[8], float c, float s) {
  float rp = r[P], rq = r[Q];
  r[P] = c * rp - s * rq;
  r[Q] = s * rp + c * rq;
  float vp = v[P], vq = v[Q];
  v[P] = c * vp - s * vq;
  v[Q] = s * vp + c * vq;
}

template <int P0,int Q0,int P1,int Q1,int P2,int Q2,int P3,int Q3>
__device__ __forceinline__ void jacobi_round(float (&r)[8], float (&v)[8], int i) {
  float c0,s0,c1,s1,c2,s2,c3,s3;
  jrot<P0,Q0>(r, c0, s0);
  jrot<P1,Q1>(r, c1, s1);
  jrot<P2,Q2>(r, c2, s2);
  jrot<P3,Q3>(r, c3, s3);
  jcol<P0,Q0>(r, v, c0, s0);
  jcol<P1,Q1>(r, v, c1, s1);
  jcol<P2,Q2>(r, v, c2, s2);
  jcol<P3,Q3>(r, v, c3, s3);
  float alpha = 1.0f, beta = 0.0f;
  int plane = i;
  if (i == P0) { alpha = c0; beta = -s0; plane = Q0; }
  if (i == Q0) { alpha = c0; beta =  s0; plane = P0; }
  if (i == P1) { alpha = c1; beta = -s1; plane = Q1; }
  if (i == Q1) { alpha = c1; beta =  s1; plane = P1; }
  if (i == P2) { alpha = c2; beta = -s2; plane = Q2; }
  if (i == Q2) { alpha = c2; beta =  s2; plane = P2; }
  if (i == P3) { alpha = c3; beta = -s3; plane = Q3; }
  if (i == Q3) { alpha = c3; beta =  s3; plane = P3; }
  float prow[8];
#pragma unroll
  for (int j = 0; j < 8; ++j) prow[j] = __shfl(r[j], plane, 64);
#pragma unroll
  for (int j = 0; j < 8; ++j) r[j] = alpha * r[j] + beta * prow[j];
}

// ------- Kernel C: redundant per-block eigensolve (wave 0) + quad projection -------
__global__ __launch_bounds__(TPB, 4)
void project_solve_kernel(const float* __restrict__ x,
                          const double* __restrict__ sums_d,
                          float* __restrict__ out,
                          float* __restrict__ out_tail) {
  __shared__ double sums[NACC];
  __shared__ float s_res[9];
  int t = threadIdx.x;

  if (t < NACC) sums[t] = sums_d[t];
  __syncthreads();

  if (t < 64) {   // wave 0 solves; waves 1-3 wait at the barrier
    const int i = t & 7;
    const double invN = 1.0 / (double)NB;
    double mean[8];
#pragma unroll
    for (int j = 0; j < 8; ++j) mean[j] = sums[j] * invN;
    double mean_i = mean[0];
#pragma unroll
    for (int k = 1; k < 8; ++k) if (i == k) mean_i = mean[k];
    double rowd[8];
#pragma unroll
    for (int j = 0; j < 8; ++j) {
      int p = i < j ? i : j;
      int q = i < j ? j : i;
      int idx = 8 + p * 8 - (p * (p - 1)) / 2 + (q - p);
      rowd[j] = sums[idx] - (double)NB * mean_i * mean[j];
    }
    double tr = 0.0;
#pragma unroll
    for (int k = 0; k < 8; ++k) tr += __shfl(rowd[k], k, 64);
    double shift = tr * 0.125;

    float r[8], v[8];
#pragma unroll
    for (int j = 0; j < 8; ++j) {
      double d = rowd[j] - (j == i ? shift : 0.0);
      r[j] = (float)(d * (1.0 / 1536.0));
      v[j] = (j == i) ? 1.0f : 0.0f;
    }
#pragma unroll 1
    for (int sweep = 0; sweep < 5; ++sweep) {
      jacobi_round<7,0, 1,6, 2,5, 3,4>(r, v, i);
      jacobi_round<7,1, 2,0, 3,6, 4,5>(r, v, i);
      jacobi_round<7,2, 3,1, 4,0, 5,6>(r, v, i);
      jacobi_round<7,3, 4,2, 5,1, 6,0>(r, v, i);
      jacobi_round<7,4, 5,3, 6,2, 0,1>(r, v, i);
      jacobi_round<7,5, 6,4, 0,3, 1,2>(r, v, i);
      jacobi_round<7,6, 0,5, 1,4, 2,3>(r, v, i);
    }
    float diag[8];
#pragma unroll
    for (int k = 0; k < 8; ++k) diag[k] = rdlane(r[k], k);
    int best = 0; float bd = diag[0];
#pragma unroll
    for (int k = 1; k < 8; ++k) if (diag[k] > bd) { bd = diag[k]; best = k; }
    float vi = v[0];
#pragma unroll
    for (int k = 1; k < 8; ++k) if (best == k) vi = v[k];
    float vec[8];
#pragma unroll
    for (int k = 0; k < 8; ++k) vec[k] = rdlane(vi, k);
    float nrm2 = 0.0f;
#pragma unroll
    for (int k = 0; k < 8; ++k) nrm2 += vec[k] * vec[k];
    float inv = 1.0f / sqrtf(nrm2);
#pragma unroll
    for (int k = 0; k < 8; ++k) vec[k] *= inv;
    // sign convention (measured vs LAPACK round 1/2): largest-|component| NEGATIVE
    int m = 0; float am = fabsf(vec[0]);
#pragma unroll
    for (int k = 1; k < 8; ++k) { float aa = fabsf(vec[k]); if (aa > am) { am = aa; m = k; } }
    float vm = vec[0];
#pragma unroll
    for (int k = 1; k < 8; ++k) if (m == k) vm = vec[k];
    if (vm > 0.0f) {
#pragma unroll
      for (int k = 0; k < 8; ++k) vec[k] = -vec[k];
    }
    double c0d = 0.0;
#pragma unroll
    for (int k = 0; k < 8; ++k) c0d += mean[k] * (double)vec[k];
    float mi = (float)mean[0];
#pragma unroll
    for (int k = 1; k < 8; ++k) if (i == k) mi = (float)mean[k];
    float vl = vec[0];
#pragma unroll
    for (int k = 1; k < 8; ++k) if (i == k) vl = vec[k];

    if (t < 8) {
      s_res[t] = vl;
      if (blockIdx.x == 0) {
        out_tail[t]     = mi;   // mean
        out_tail[8 + t] = vl;   // pca_components
      }
    }
    if (t == 0) s_res[8] = (float)c0d;
  }
  __syncthreads();

  // quad projection: compile-time 3 iters, 8x float4 loads -> float4 store
  float w0 = s_res[0], w1 = s_res[1], w2 = s_res[2], w3 = s_res[3];
  float w4 = s_res[4], w5 = s_res[5], w6 = s_res[6], w7 = s_res[7];
  float c0 = s_res[8];
  float4* out4 = (float4*)out;
  int tid = blockIdx.x * TPB + t;
#pragma unroll
  for (int it = 0; it < 3; ++it) {
    int q = tid + it * STRIDE;
    int hq = q % 24;
    int t1 = q / 24;
    int wo = t1 % 96;
    int t2 = t1 / 96;
    int so = t2 % 32;
    int b  = t2 / 32;
    const float* base = x + (((b * 64 + 2 * so) * 192 + 2 * wo) * 192 + 8 * hq);
    float4 a0 = *(const float4*)(base);
    float4 b0 = *(const float4*)(base + 4);
    float4 a1 = *(const float4*)(base + 192);
    float4 b1 = *(const float4*)(base + 196);
    float4 a2 = *(const float4*)(base + 192 * 192);
    float4 b2 = *(const float4*)(base + 192 * 192 + 4);
    float4 a3 = *(const float4*)(base + 192 * 192 + 192);
    float4 b3 = *(const float4*)(base + 192 * 192 + 196);
    float o0 = a0.x * w0 + a0.y * w1 + a1.x * w2 + a1.y * w3
             + a2.x * w4 + a2.y * w5 + a3.x * w6 + a3.y * w7 - c0;
    float o1 = a0.z * w0 + a0.w * w1 + a1.z * w2 + a1.w * w3
             + a2.z * w4 + a2.w * w5 + a3.z * w6 + a3.w * w7 - c0;
    float o2 = b0.x * w0 + b0.y * w1 + b1.x * w2 + b1.y * w3
             + b2.x * w4 + b2.y * w5 + b3.x * w6 + b3.y * w7 - c0;
    float o3 = b0.z * w0 + b0.w * w1 + b1.z * w2 + b1.w * w3
             + b2.z * w4 + b2.w * w5 + b3.z * w6 + b3.w * w7 - c0;
    out4[q] = make_float4(o0, o1, o2, o3);
  }
}

extern "C" void kernel_launch(void* const* d_in, const int* in_sizes, int n_in,
                              void* d_out, int out_size, void* d_ws, size_t ws_size,
                              hipStream_t stream) {
  (void)in_sizes; (void)n_in; (void)out_size; (void)ws_size;
  const float* x = (const float*)d_in[0];
  float* out = (float*)d_out;
  float* partials = (float*)d_ws;                        // 44*768 f32 = 135 KB
  double* sums_d  = (double*)(partials + NACC * GRID_A); // 44 f64 (8B-aligned)

  reduce_kernel<<<GRID_A, TPB, 0, stream>>>(x, partials);
  mid_reduce_kernel<<<NACC, TPB, 0, stream>>>(partials, sums_d);
  project_solve_kernel<<<GRID_P, TPB, 0, stream>>>(x, sums_d, out, out + NB);
}